// Round 8
// baseline (394.199 us; speedup 1.0000x reference)
//
#include <hip/hip_runtime.h>
#include <hip/hip_bf16.h>

#define BB 2
#define CC 512
#define HH 14
#define WW 14
#define PP 196
#define NSEQ 8
#define NSLICE 8                 // worker WGs per row (64 ch each)
#define NWORK (14 * NSLICE)      // 112
#define FW 16                    // dwords per flag/ds line (64B)
#define NZERO (3 * PP * FW)      // uflag + hflag + dsAcc (all zeroed)
#define ALL8 0x0101010101010101ull

// flags (round 8): uflag[cell*64 + w*8 + wv] = 1 byte per (slice w, wave wv)
//   publish. Consumer wave wv needs slice wv's 8-byte word (its channels'
//   producers). dsAcc readiness needs the full 64B line (all slices) -- wave 0
//   of each worker WG observes it and LDS-broadcasts the 16 rcp'd denominators.
// hflag[cell*64 + s] = 1 byte per bulk-wave publish (8 bytes == h_bulk ready).

// ---------------------------------------------------------------------------
// prep: gemm_a (224 WGs) + transpose_wh (256 WGs) + flag/dsAcc zero (1 WG)
// ---------------------------------------------------------------------------
__global__ __launch_bounds__(256) void prep(
    const float* __restrict__ Wx, const float* __restrict__ X,
    const float* __restrict__ b_in, const float* __restrict__ Wh,
    float* __restrict__ A, float* __restrict__ WhT,
    unsigned* __restrict__ cnts /* uflag, hflag, dsAcc contiguous */) {
    __shared__ float Ws[32][33], Xs[32][33];
    int bid = blockIdx.x;
    int t = threadIdx.x;
    if (bid < 224) {
        int z = bid / 112, rem = bid % 112;
        int c0 = (rem % 16) * 32, p0 = (rem / 16) * 32;
        int tx = t % 32, ty = t / 32;
        int pl = (t % 16) * 2, cl = (t / 16) * 2;
        float acc[2][2] = {{0.f,0.f},{0.f,0.f}};
        for (int k0 = 0; k0 < CC; k0 += 32) {
            #pragma unroll
            for (int r = 0; r < 4; ++r)
                Ws[ty + 8*r][tx] = Wx[(size_t)(c0 + ty + 8*r) * CC + k0 + tx];
            #pragma unroll
            for (int r = 0; r < 4; ++r) {
                int p = p0 + tx, k = k0 + ty + 8*r;
                Xs[ty + 8*r][tx] = (p < PP) ? X[((size_t)z * CC + k) * PP + p] : 0.f;
            }
            __syncthreads();
            #pragma unroll
            for (int k = 0; k < 32; ++k) {
                float w0 = Ws[cl][k], w1 = Ws[cl+1][k];
                float x0 = Xs[k][pl], x1 = Xs[k][pl+1];
                acc[0][0] += w0*x0; acc[0][1] += w0*x1;
                acc[1][0] += w1*x0; acc[1][1] += w1*x1;
            }
            __syncthreads();
        }
        #pragma unroll
        for (int i = 0; i < 2; ++i)
            #pragma unroll
            for (int j = 0; j < 2; ++j) {
                int c = c0 + cl + i, p = p0 + pl + j;
                if (p < PP) A[((size_t)z * PP + p) * CC + c] = acc[i][j] + b_in[c];
            }
    } else if (bid < 480) {
        int tid = bid - 224;
        int c0 = (tid % 16) * 32, k0 = (tid / 16) * 32;
        int tx = t % 32, ty = t / 32;
        #pragma unroll
        for (int r = 0; r < 4; ++r)
            Ws[ty + 8*r][tx] = Wh[(size_t)(c0 + ty + 8*r) * CC + k0 + tx];
        __syncthreads();
        #pragma unroll
        for (int r = 0; r < 4; ++r)
            WhT[(size_t)(k0 + ty + 8*r) * CC + c0 + tx] = Ws[tx][ty + 8*r];
    } else {
        for (int i = t; i < NZERO; i += 256) cnts[i] = 0u;
    }
}

// ---------------------------------------------------------------------------
// sync primitives
// ---------------------------------------------------------------------------
__device__ __forceinline__ unsigned long long flag8_ld(const unsigned char* f) {
    return __hip_atomic_load((const unsigned long long*)f, __ATOMIC_RELAXED,
                             __HIP_MEMORY_SCOPE_AGENT);
}
__device__ __forceinline__ void flag_st(unsigned char* f) {
    __hip_atomic_store(f, (unsigned char)1, __ATOMIC_RELAXED,
                       __HIP_MEMORY_SCOPE_AGENT);
}
__device__ __forceinline__ float ldf_agent(const float* p) {
    return __hip_atomic_load(p, __ATOMIC_RELAXED, __HIP_MEMORY_SCOPE_AGENT);
}
__device__ __forceinline__ void store_wt(float* p, float v) {
    __hip_atomic_store(p, v, __ATOMIC_RELAXED, __HIP_MEMORY_SCOPE_AGENT);
}
// full 64B line of per-(slice,wave) flags ready?
__device__ __forceinline__ bool line_rdy(const unsigned char* f) {
    #pragma unroll
    for (int i = 0; i < 8; ++i)
        if (flag8_ld(f + i * 8) != ALL8) return false;
    return true;
}

// one window pixel for 8 channels (this wave's seq); E = exp(U) input
__device__ __forceinline__ void pix(const float4 E0, const float4 E1,
                                    const float* ar, const float* er, float* hacc) {
    float ee[8] = {E0.x,E0.y,E0.z,E0.w,E1.x,E1.y,E1.z,E1.w};
    float ds = 0.f, tl[8];
    #pragma unroll
    for (int j = 0; j < 8; ++j) {
        float sv = ar[j] + __logf(ee[j]);
        float pv = er[j] * ee[j];
        ds += fmaxf(pv, 1.0f);
        tl[j] = fmaxf(sv, 0.0f) * pv;
    }
    #pragma unroll
    for (int off = 32; off; off >>= 1) ds += __shfl_xor(ds, off, 64);
    float rd = 1.0f / ds;
    #pragma unroll
    for (int j = 0; j < 8; ++j) hacc[j] += tl[j] * rd;
}

// process n pixels at rowp + y*CC, 4-deep pipelined plain loads
__device__ __forceinline__ void proc_row(const float* __restrict__ rowp, int n,
                                         const float* ar, const float* er, float* hacc) {
    float4 cur[4][2];
    int y = 0, curn = (n < 4) ? n : 4;
    #pragma unroll
    for (int i = 0; i < 4; ++i) if (i < curn) {
        cur[i][0] = *(const float4*)(rowp + (size_t)i * CC);
        cur[i][1] = *(const float4*)(rowp + (size_t)i * CC + 256);
    }
    while (true) {
        int yn = y + curn;
        int rem = n - yn;
        int nextn = (rem < 4) ? rem : 4;
        float4 nxt[4][2];
        #pragma unroll
        for (int i = 0; i < 4; ++i) if (i < nextn) {
            nxt[i][0] = *(const float4*)(rowp + (size_t)(yn + i) * CC);
            nxt[i][1] = *(const float4*)(rowp + (size_t)(yn + i) * CC + 256);
        }
        #pragma unroll
        for (int i = 0; i < 4; ++i) if (i < curn)
            pix(cur[i][0], cur[i][1], ar, er, hacc);
        if (nextn <= 0) break;
        #pragma unroll
        for (int i = 0; i < 4; ++i) if (i < nextn) {
            cur[i][0] = nxt[i][0]; cur[i][1] = nxt[i][1];
        }
        curn = nextn; y = yn;
    }
}

// ---------------------------------------------------------------------------
// Round 8 worker: wave-decoupled cell pipeline. ONE WG barrier per cell (the
// up[] matvec-partial exchange, double-buffered by py parity). Per-wave byte
// flags set right after each wave's own vmcnt(0) -- no WG-wide drain barrier,
// no phase barriers, no pf-verdict leg. Wave 0 owns the all-slice dsAcc
// observe (full 64B lines) and LDS-broadcasts the 16 rcp'd denominators;
// other waves spin on an LDS word (on-chip, cheap). hb prefetch is per-wave
// and ballot-uniform (no conditional barriers anywhere -> divergence-safe by
// construction, round-5 lesson).
// ---------------------------------------------------------------------------
__global__ __launch_bounds__(512, 2) void rnn_dataflow(
    const float* __restrict__ A, const float* __restrict__ WhT,
    float* __restrict__ E, float* __restrict__ h_bulk,
    float* __restrict__ h_t, float* __restrict__ TLN,
    float* __restrict__ TLW, float* __restrict__ dsAcc,
    unsigned char* __restrict__ uflag, unsigned char* __restrict__ hflag) {
    __shared__ __align__(16) float hT8[CC * 8];    // full h [k][s], stride 8
    __shared__ __align__(16) float up2[2][8 * 576]; // matvec partials, dbuf by parity
    __shared__ float dsrL[2][16];                  // rcp'd denominators [parity]
    __shared__ int   dsfl[2];                      // LDS ds-ready markers (cell+1)
    __shared__ unsigned mbox;                      // bulk WG: ready-chunks bitmap
    int bid = blockIdx.x;
    int t = threadIdx.x;
    int lane = t & 63, wv = t >> 6;

    if (bid < NWORK) {
        // ================= row worker =================
        int px = bid >> 3, w = bid & 7;
        int ch = w * 64 + lane;                   // this thread's publish channel
        int m = wv >> 1, b = wv & 1;              // seq decode (s = wv)
        float wreg2[64];                          // WhT[64wv+kk][ch]
        #pragma unroll
        for (int kk = 0; kk < 64; ++kk)
            wreg2[kk] = WhT[(size_t)(wv * 64 + kk) * CC + ch];
        if (t < 2) dsfl[t] = 0;
        __syncthreads();                          // dsfl init visible
        __builtin_amdgcn_s_setprio(1);

        float hb[8];
        bool hb_ok = false;                       // per-wave, ballot-uniform

        for (int py = 0; py < WW; ++py) {
            int cell = px * WW + py;
            int cellN = cell - WW, cellW = cell - 1;
            int par = py & 1;

            // prefetch consumer-cell a values (overlaps the polls)
            float aSr = 0.f, aWr = 0.f;
            if (px < HH - 1) {
                int fi = (m & 2) ? (HH - 2 - px) : (px + 1);
                int fj = (m & 1) ? (WW - 1 - py) : py;
                aSr = A[((size_t)b * PP + fi * WW + fj) * CC + ch];
            }
            if (py < WW - 1) {
                int fi = (m & 2) ? (HH - 1 - px) : px;
                int fj = (m & 1) ? (WW - 2 - py) : (py + 1);
                aWr = A[((size_t)b * PP + fi * WW + fj) * CC + ch];
            }

            // per-wave poll. wave 0 observes FULL lines (needed for dsAcc);
            // waves 1-7 observe only their own slice word (their channels).
            bool needH = !hb_ok;
            if (wv == 0) {
                while (true) {
                    bool rdy = true;
                    if (lane < 8)        { if (py > 0) rdy = (flag8_ld(uflag + (size_t)cellW * 64 + lane * 8) == ALL8); }
                    else if (lane < 16)  { if (px > 0) rdy = (flag8_ld(uflag + (size_t)cellN * 64 + (lane - 8) * 8) == ALL8); }
                    else if (lane == 16) { if (needH)  rdy = (flag8_ld(hflag + (size_t)cell * 64) == ALL8); }
                    if (__ballot(rdy) == ~0ull) break;
                    __builtin_amdgcn_s_sleep(1);
                }
            } else {
                while (true) {
                    bool rdy = true;
                    if (lane == 0)      { if (py > 0) rdy = (flag8_ld(uflag + (size_t)cellW * 64 + wv * 8) == ALL8); }
                    else if (lane == 1) { if (px > 0) rdy = (flag8_ld(uflag + (size_t)cellN * 64 + wv * 8) == ALL8); }
                    else if (lane == 2) { if (needH)  rdy = (flag8_ld(hflag + (size_t)cell * 64) == ALL8); }
                    if (__ballot(rdy) == ~0ull) break;
                    __builtin_amdgcn_s_sleep(1);
                }
            }
            asm volatile("" ::: "memory");

            // per-wave batched loads (issued before the ds wait)
            if (needH) {
                #pragma unroll
                for (int s = 0; s < 8; ++s)
                    hb[s] = h_bulk[((size_t)cell * NSEQ + s) * CC + t];
            }
            float tn[8], tw[8];
            if (px > 0) {
                #pragma unroll
                for (int s = 0; s < 8; ++s)
                    tn[s] = ldf_agent(&TLN[((size_t)cell * NSEQ + s) * CC + t]);
            }
            if (py > 0) {
                #pragma unroll
                for (int s = 0; s < 8; ++s)
                    tw[s] = ldf_agent(&TLW[((size_t)cell * NSEQ + s) * CC + t]);
            }

            // denominators: wave 0 loads + rcp + LDS broadcast; others spin LDS
            if (px > 0 || py > 0) {
                if (wv == 0) {
                    float rv = 0.f;
                    if (lane < 16)
                        rv = __builtin_amdgcn_rcpf(ldf_agent(&dsAcc[(size_t)cell * 16 + lane]));
                    if (lane < 16) dsrL[par][lane] = rv;
                    asm volatile("s_waitcnt lgkmcnt(0)" ::: "memory");
                    __hip_atomic_store(&dsfl[par], cell + 1, __ATOMIC_RELAXED,
                                       __HIP_MEMORY_SCOPE_WORKGROUP);
                } else {
                    while (__hip_atomic_load(&dsfl[par], __ATOMIC_RELAXED,
                                             __HIP_MEMORY_SCOPE_WORKGROUP) != cell + 1)
                        __builtin_amdgcn_s_sleep(0);
                    asm volatile("" ::: "memory");
                }
                if (px > 0) {
                    #pragma unroll
                    for (int s = 0; s < 8; ++s) hb[s] += tn[s] * dsrL[par][s];
                }
                if (py > 0) {
                    #pragma unroll
                    for (int s = 0; s < 8; ++s) hb[s] += tw[s] * dsrL[par][8 + s];
                }
            }
            if (wv == w) {   // h_t: this slice's own 64-ch stripe only
                #pragma unroll
                for (int s = 0; s < 8; ++s)
                    h_t[((size_t)cell * NSEQ + s) * CC + t] = hb[s];
            }
            *(float4*)&hT8[t * 8]     = make_float4(hb[0], hb[1], hb[2], hb[3]);
            *(float4*)&hT8[t * 8 + 4] = make_float4(hb[4], hb[5], hb[6], hb[7]);
            if (cell == PP - 1) break;           // (13,13): no U consumer

            // matvec: wave wv owns k in [64wv,64wv+64); reads OWN hT8 stripe
            float acc[8] = {0.f,0.f,0.f,0.f,0.f,0.f,0.f,0.f};
            const float* hp = hT8 + (wv << 9);
            #pragma unroll
            for (int kk = 0; kk < 64; ++kk) {
                float4 h0 = *(const float4*)(hp + kk * 8);
                float4 h1 = *(const float4*)(hp + kk * 8 + 4);
                float wvv = wreg2[kk];
                acc[0] += wvv * h0.x; acc[1] += wvv * h0.y;
                acc[2] += wvv * h0.z; acc[3] += wvv * h0.w;
                acc[4] += wvv * h1.x; acc[5] += wvv * h1.y;
                acc[6] += wvv * h1.z; acc[7] += wvv * h1.w;
            }
            float* upp = up2[par];
            #pragma unroll
            for (int s = 0; s < 8; ++s)
                upp[wv * 576 + lane * 9 + s] = acc[s];
            __syncthreads();                      // THE one WG barrier per cell

            // publish (per-wave from here on): U, E, tails, ds partials
            {
                float U = upp[lane * 9 + wv];
                #pragma unroll
                for (int w2 = 1; w2 < 8; ++w2) U += upp[w2 * 576 + lane * 9 + wv];
                float Ev = __expf(U);
                store_wt(&E[((size_t)wv * PP + cell) * CC + ch], Ev);
                float pdS = 0.f, pdW = 0.f;
                if (px < HH - 1) {
                    float pv = __expf(aSr) * Ev;
                    store_wt(&TLN[((size_t)(cell + WW) * NSEQ + wv) * CC + ch],
                             fmaxf(aSr + U, 0.f) * pv);
                    pdS = fmaxf(pv, 1.f);
                }
                if (py < WW - 1) {
                    float pv = __expf(aWr) * Ev;
                    store_wt(&TLW[((size_t)(cell + 1) * NSEQ + wv) * CC + ch],
                             fmaxf(aWr + U, 0.f) * pv);
                    pdW = fmaxf(pv, 1.f);
                }
                #pragma unroll
                for (int off = 32; off; off >>= 1) {
                    pdS += __shfl_xor(pdS, off, 64);
                    pdW += __shfl_xor(pdW, off, 64);
                }
                if (lane == 0) {
                    if (px < HH - 1)
                        unsafeAtomicAdd(&dsAcc[(size_t)(cell + WW) * 16 + wv], pdS);
                    if (py < WW - 1)
                        unsafeAtomicAdd(&dsAcc[(size_t)(cell + 1) * 16 + 8 + wv], pdW);
                }
            }
            __builtin_amdgcn_s_waitcnt(0);        // own wave's stores/atomics acked
            asm volatile("" ::: "memory");
            if (lane == 0) flag_st(uflag + (size_t)cell * 64 + w * 8 + wv);

            // per-wave hb prefetch for cell+1 (ballot-uniform verdict)
            hb_ok = false;
            if (py + 1 < WW) {
                bool f = (flag8_ld(hflag + (size_t)(cell + 1) * 64) == ALL8);
                if (__ballot(f) == ~0ull) {
                    #pragma unroll
                    for (int s = 0; s < 8; ++s)
                        hb[s] = h_bulk[((size_t)(cell + 1) * NSEQ + s) * CC + t];
                    hb_ok = true;
                }
            }
        }
    } else {
        // ================= bulk window WG (chunked rows), off-path ==========
        int cell = bid - NWORK;
        int px = cell / WW, py = cell % WW;
        int s = wv, m = s >> 1, b = s & 1;
        int fi = (m & 2) ? (HH-1-px) : px;
        int fj = (m & 1) ? (WW-1-py) : py;
        int cb = lane * 4;

        if (t == 0) mbox = 0u;
        __syncthreads();          // once, at WG start (long before deps ready)

        const float* acur = A + ((size_t)b * PP + fi * WW + fj) * CC;
        float4 a0 = *(const float4*)(acur + cb);
        float4 a1 = *(const float4*)(acur + cb + 256);
        float ar[8] = {a0.x,a0.y,a0.z,a0.w,a1.x,a1.y,a1.z,a1.w};
        float er[8];
        #pragma unroll
        for (int j = 0; j < 8; ++j) er[j] = __expf(ar[j]);
        float hacc[8] = {0.f,0.f,0.f,0.f,0.f,0.f,0.f,0.f};

        {   // self pixel first (needs no U at all): U=0 -> E=1
            float ds = 0.f, tl[8];
            #pragma unroll
            for (int j = 0; j < 8; ++j) {
                float pv = er[j];
                ds += fmaxf(pv, 1.0f);
                tl[j] = fmaxf(ar[j], 0.0f) * pv;
            }
            #pragma unroll
            for (int off = 32; off; off >>= 1) ds += __shfl_xor(ds, off, 64);
            float rd = 1.0f / ds;
            #pragma unroll
            for (int j = 0; j < 8; ++j) hacc[j] += tl[j] * rd;
        }

        const float* Eb = E + (size_t)s * PP * CC;
        // chunk slots: slot = lane, row x = lane>>1, phase = lane&1.
        // row limit L: x<=px-2 -> py ; x=px-1 -> py-1 ; x=px -> py-2
        //   L<=2 : single chunk [0..L]    gate (x,L)     at slot (2x+0)
        //   L>2  : early [0..L-3]         gate (x,L-3)   at slot (2x+0)
        //          late  [L-2..L] (3 px)  gate (x,L)     at slot (2x+1)
        int sx = lane >> 1, sph = lane & 1;
        int gate = -1;
        if (sx <= px) {
            int L = (sx <= px-2) ? py : ((sx == px-1) ? py-1 : py-2);
            if (L >= 0) {
                if (L <= 2) { if (sph == 0) gate = sx * WW + L; }
                else gate = sx * WW + (sph ? L : (L - 3));
            }
        }
        unsigned pend = (unsigned)__ballot(gate >= 0);

        if (wv == 0) {
            // sole fabric poller: lane l checks its chunk's full gate line
            unsigned done = 0u;
            while (pend) {
                bool rdy = true;
                if (gate >= 0 && ((pend >> lane) & 1u))
                    rdy = line_rdy(uflag + (size_t)gate * 64);
                unsigned newly = pend & (unsigned)__ballot(rdy);
                if (!newly) { __builtin_amdgcn_s_sleep(2); continue; }
                done |= newly;
                __hip_atomic_store(&mbox, done, __ATOMIC_RELAXED,
                                   __HIP_MEMORY_SCOPE_WORKGROUP);
                asm volatile("" ::: "memory");
                unsigned go = newly;
                while (go) {
                    int sl = __ffs(go) - 1; go &= go - 1;
                    int xx = sl >> 1;
                    int L = (xx <= px-2) ? py : ((xx == px-1) ? py-1 : py-2);
                    int yy0 = 0, yy1 = L;
                    if (L > 2) { if (sl & 1) yy0 = L - 2; else yy1 = L - 3; }
                    proc_row(Eb + (size_t)(xx * WW + yy0) * CC + cb,
                             yy1 - yy0 + 1, ar, er, hacc);
                }
                pend &= ~newly;
            }
        } else {
            while (pend) {
                unsigned d = __hip_atomic_load(&mbox, __ATOMIC_RELAXED,
                                               __HIP_MEMORY_SCOPE_WORKGROUP);
                unsigned newly = d & pend;
                if (!newly) { __builtin_amdgcn_s_sleep(2); continue; }
                asm volatile("" ::: "memory");
                unsigned go = newly;
                while (go) {
                    int sl = __ffs(go) - 1; go &= go - 1;
                    int xx = sl >> 1;
                    int L = (xx <= px-2) ? py : ((xx == px-1) ? py-1 : py-2);
                    int yy0 = 0, yy1 = L;
                    if (L > 2) { if (sl & 1) yy0 = L - 2; else yy1 = L - 3; }
                    proc_row(Eb + (size_t)(xx * WW + yy0) * CC + cb,
                             yy1 - yy0 + 1, ar, er, hacc);
                }
                pend &= ~newly;
            }
        }

        // per-wave publish h_bulk: contiguous WT stores + drain + byte flag
        float* hp = h_bulk + ((size_t)cell * NSEQ + s) * CC;
        #pragma unroll
        for (int j = 0; j < 4; ++j) {
            store_wt(hp + cb + j,       hacc[j]);
            store_wt(hp + cb + 256 + j, hacc[4 + j]);
        }
        __builtin_amdgcn_s_waitcnt(0);
        asm volatile("" ::: "memory");
        if (lane == 0) flag_st(hflag + (size_t)cell * 64 + s);
    }
}

// ---------------------------------------------------------------------------
// gemm_y: Y[b][p][c] = sum_k Wo[c][k] * (sum_m h_t[p][2m+b][k]) + 4*b_out[c]
// ---------------------------------------------------------------------------
__global__ __launch_bounds__(256) void gemm_y(
    const float* __restrict__ Wo, const float* __restrict__ h_t,
    const float* __restrict__ b_out, float* __restrict__ Y) {
    __shared__ float Ws[32][33], Hs[32][33];
    int b  = blockIdx.z;
    int c0 = blockIdx.x * 32, p0 = blockIdx.y * 32;
    int t  = threadIdx.x;
    int tx = t % 32, ty = t / 32;
    int pl = (t % 16) * 2, cl = (t / 16) * 2;
    float acc[2][2] = {{0.f,0.f},{0.f,0.f}};
    for (int k0 = 0; k0 < CC; k0 += 32) {
        #pragma unroll
        for (int r = 0; r < 4; ++r)
            Ws[ty + 8*r][tx] = Wo[(size_t)(c0 + ty + 8*r) * CC + k0 + tx];
        #pragma unroll
        for (int r = 0; r < 4; ++r) {
            int p = p0 + ty + 8*r;
            float v = 0.f;
            if (p < PP) {
                size_t base = (size_t)p * NSEQ * CC + k0 + tx;
                v = h_t[base + (size_t)(0 + b) * CC]
                  + h_t[base + (size_t)(2 + b) * CC]
                  + h_t[base + (size_t)(4 + b) * CC]
                  + h_t[base + (size_t)(6 + b) * CC];
            }
            Hs[tx][ty + 8*r] = v;
        }
        __syncthreads();
        #pragma unroll
        for (int k = 0; k < 32; ++k) {
            float w0 = Ws[cl][k], w1 = Ws[cl+1][k];
            float h0 = Hs[k][pl], h1 = Hs[k][pl+1];
            acc[0][0] += w0*h0; acc[0][1] += w0*h1;
            acc[1][0] += w1*h0; acc[1][1] += w1*h1;
        }
        __syncthreads();
    }
    #pragma unroll
    for (int i = 0; i < 2; ++i)
        #pragma unroll
        for (int j = 0; j < 2; ++j) {
            int cc = c0 + cl + i, p = p0 + pl + j;
            if (p < PP) Y[((size_t)b * PP + p) * CC + cc] = acc[i][j] + 4.0f * b_out[cc];
        }
}

// ---------------------------------------------------------------------------
// softmax over channels -> out[b][c][p]
// ---------------------------------------------------------------------------
__global__ __launch_bounds__(256) void softmax_out(
    const float* __restrict__ Y, float* __restrict__ out) {
    int wave = threadIdx.x >> 6, lane = threadIdx.x & 63;
    int idx = blockIdx.x * 4 + wave;
    if (idx >= BB * PP) return;
    int b = idx / PP, p = idx % PP;
    const float* y = Y + ((size_t)b * PP + p) * CC;
    float v[8];
    float mx = -3.4e38f;
    #pragma unroll
    for (int j = 0; j < 8; ++j) { v[j] = y[lane + 64*j]; mx = fmaxf(mx, v[j]); }
    #pragma unroll
    for (int off = 32; off; off >>= 1) mx = fmaxf(mx, __shfl_xor(mx, off, 64));
    float sum = 0.f;
    #pragma unroll
    for (int j = 0; j < 8; ++j) { v[j] = expf(v[j] - mx); sum += v[j]; }
    #pragma unroll
    for (int off = 32; off; off >>= 1) sum += __shfl_xor(sum, off, 64);
    float r = 1.0f / sum;
    #pragma unroll
    for (int j = 0; j < 8; ++j)
        out[((size_t)b * CC + lane + 64*j) * PP + p] = v[j] * r;
}

// ---------------------------------------------------------------------------
extern "C" void kernel_launch(void* const* d_in, const int* in_sizes, int n_in,
                              void* d_out, int out_size, void* d_ws, size_t ws_size,
                              hipStream_t stream) {
    const float* X     = (const float*)d_in[0];
    const float* Wx    = (const float*)d_in[1];
    const float* Wh    = (const float*)d_in[2];
    const float* b_in  = (const float*)d_in[3];
    const float* Wo    = (const float*)d_in[4];
    const float* b_out = (const float*)d_in[5];
    float* out = (float*)d_out;

    float* ws     = (float*)d_ws;
    float* WhT    = ws;                     // 262144
    float* A      = WhT    + 262144;        // 200704
    float* E      = A      + 200704;        // 802816  [s][cell][c] = exp(U)
    float* h_bulk = E      + 802816;        // 802816  [cell][s][c]
    float* h_t    = h_bulk + 802816;        // 802816  [cell][s][c] full h
    float* TLN    = h_t    + 802816;        // 802816  [cell][s][c] tail from North
    float* TLW    = TLN    + 802816;        // 802816  [cell][s][c] tail from West
    float* Y      = TLW    + 802816;        // 200704
    unsigned char* uflag = (unsigned char*)(Y + 200704);   // PP*64 B
    unsigned char* hflag = uflag + PP * 64;                // PP*64 B
    float* dsAcc = (float*)(hflag + PP * 64);              // PP*16: [cell][N|W]

    hipLaunchKernelGGL(prep, dim3(481), dim3(256), 0, stream,
                       Wx, X, b_in, Wh, A, WhT, (unsigned*)uflag);
    hipLaunchKernelGGL(rnn_dataflow, dim3(NWORK + PP), dim3(512), 0, stream,
                       A, WhT, E, h_bulk, h_t, TLN, TLW, dsAcc, uflag, hflag);
    hipLaunchKernelGGL(gemm_y, dim3(16, 7, 2), dim3(256), 0, stream, Wo, h_t, b_out, Y);
    hipLaunchKernelGGL(softmax_out, dim3(98), dim3(256), 0, stream, Y, out);
}

// Round 9
// 319.427 us; speedup vs baseline: 1.2341x; 1.2341x over previous
//
#include <hip/hip_runtime.h>
#include <hip/hip_bf16.h>

#define BB 2
#define CC 512
#define HH 14
#define WW 14
#define PP 196
#define NSEQ 8
#define NSLICE 8                 // worker WGs per row (64 ch each)
#define NWORK (14 * NSLICE)      // 112
#define FW 16                    // dwords per flag/ds line (64B)
#define NZERO (3 * PP * FW)      // uflag + hflag + dsAcc (all zeroed)
#define ALL8 0x0101010101010101ull

// flags: uflag[cell*64 + w] = 1 byte per slice publish (8 bytes == E/TL/ds/h_t ready)
//        hflag[cell*64 + s] = 1 byte per bulk-wave publish (8 bytes == h_bulk ready)

// ---------------------------------------------------------------------------
// prep: gemm_a (224) + transpose Wh (256) + transpose Wo (256) + zero (1)
// ---------------------------------------------------------------------------
__global__ __launch_bounds__(256) void prep(
    const float* __restrict__ Wx, const float* __restrict__ X,
    const float* __restrict__ b_in, const float* __restrict__ Wh,
    const float* __restrict__ Wo,
    float* __restrict__ A, float* __restrict__ WhT, float* __restrict__ WoT,
    unsigned* __restrict__ cnts /* uflag, hflag, dsAcc contiguous */) {
    __shared__ float Ws[32][33], Xs[32][33];
    int bid = blockIdx.x;
    int t = threadIdx.x;
    if (bid < 224) {
        int z = bid / 112, rem = bid % 112;
        int c0 = (rem % 16) * 32, p0 = (rem / 16) * 32;
        int tx = t % 32, ty = t / 32;
        int pl = (t % 16) * 2, cl = (t / 16) * 2;
        float acc[2][2] = {{0.f,0.f},{0.f,0.f}};
        for (int k0 = 0; k0 < CC; k0 += 32) {
            #pragma unroll
            for (int r = 0; r < 4; ++r)
                Ws[ty + 8*r][tx] = Wx[(size_t)(c0 + ty + 8*r) * CC + k0 + tx];
            #pragma unroll
            for (int r = 0; r < 4; ++r) {
                int p = p0 + tx, k = k0 + ty + 8*r;
                Xs[ty + 8*r][tx] = (p < PP) ? X[((size_t)z * CC + k) * PP + p] : 0.f;
            }
            __syncthreads();
            #pragma unroll
            for (int k = 0; k < 32; ++k) {
                float w0 = Ws[cl][k], w1 = Ws[cl+1][k];
                float x0 = Xs[k][pl], x1 = Xs[k][pl+1];
                acc[0][0] += w0*x0; acc[0][1] += w0*x1;
                acc[1][0] += w1*x0; acc[1][1] += w1*x1;
            }
            __syncthreads();
        }
        #pragma unroll
        for (int i = 0; i < 2; ++i)
            #pragma unroll
            for (int j = 0; j < 2; ++j) {
                int c = c0 + cl + i, p = p0 + pl + j;
                if (p < PP) A[((size_t)z * PP + p) * CC + c] = acc[i][j] + b_in[c];
            }
    } else if (bid < 736) {
        int tid = bid - 224;
        const float* src = (tid < 256) ? Wh : Wo;
        float* dst = (tid < 256) ? WhT : WoT;
        tid &= 255;
        int c0 = (tid % 16) * 32, k0 = (tid / 16) * 32;
        int tx = t % 32, ty = t / 32;
        #pragma unroll
        for (int r = 0; r < 4; ++r)
            Ws[ty + 8*r][tx] = src[(size_t)(c0 + ty + 8*r) * CC + k0 + tx];
        __syncthreads();
        #pragma unroll
        for (int r = 0; r < 4; ++r)
            dst[(size_t)(k0 + ty + 8*r) * CC + c0 + tx] = Ws[tx][ty + 8*r];
    } else {
        for (int i = t; i < NZERO; i += 256) cnts[i] = 0u;
    }
}

// ---------------------------------------------------------------------------
// sync primitives
// ---------------------------------------------------------------------------
__device__ __forceinline__ unsigned long long flag8_ld(const unsigned char* f) {
    return __hip_atomic_load((const unsigned long long*)f, __ATOMIC_RELAXED,
                             __HIP_MEMORY_SCOPE_AGENT);
}
__device__ __forceinline__ void flag_st(unsigned char* f) {
    __hip_atomic_store(f, (unsigned char)1, __ATOMIC_RELAXED,
                       __HIP_MEMORY_SCOPE_AGENT);
}
__device__ __forceinline__ float ldf_agent(const float* p) {
    return __hip_atomic_load(p, __ATOMIC_RELAXED, __HIP_MEMORY_SCOPE_AGENT);
}
__device__ __forceinline__ void store_wt(float* p, float v) {
    __hip_atomic_store(p, v, __ATOMIC_RELAXED, __HIP_MEMORY_SCOPE_AGENT);
}

// one window pixel for 8 channels (this wave's seq); E = exp(U) input
__device__ __forceinline__ void pix(const float4 E0, const float4 E1,
                                    const float* ar, const float* er, float* hacc) {
    float ee[8] = {E0.x,E0.y,E0.z,E0.w,E1.x,E1.y,E1.z,E1.w};
    float ds = 0.f, tl[8];
    #pragma unroll
    for (int j = 0; j < 8; ++j) {
        float sv = ar[j] + __logf(ee[j]);
        float pv = er[j] * ee[j];
        ds += fmaxf(pv, 1.0f);
        tl[j] = fmaxf(sv, 0.0f) * pv;
    }
    #pragma unroll
    for (int off = 32; off; off >>= 1) ds += __shfl_xor(ds, off, 64);
    float rd = 1.0f / ds;
    #pragma unroll
    for (int j = 0; j < 8; ++j) hacc[j] += tl[j] * rd;
}

// process n pixels at rowp + y*CC, 4-deep pipelined plain loads
__device__ __forceinline__ void proc_row(const float* __restrict__ rowp, int n,
                                         const float* ar, const float* er, float* hacc) {
    float4 cur[4][2];
    int y = 0, curn = (n < 4) ? n : 4;
    #pragma unroll
    for (int i = 0; i < 4; ++i) if (i < curn) {
        cur[i][0] = *(const float4*)(rowp + (size_t)i * CC);
        cur[i][1] = *(const float4*)(rowp + (size_t)i * CC + 256);
    }
    while (true) {
        int yn = y + curn;
        int rem = n - yn;
        int nextn = (rem < 4) ? rem : 4;
        float4 nxt[4][2];
        #pragma unroll
        for (int i = 0; i < 4; ++i) if (i < nextn) {
            nxt[i][0] = *(const float4*)(rowp + (size_t)(yn + i) * CC);
            nxt[i][1] = *(const float4*)(rowp + (size_t)(yn + i) * CC + 256);
        }
        #pragma unroll
        for (int i = 0; i < 4; ++i) if (i < curn)
            pix(cur[i][0], cur[i][1], ar, er, hacc);
        if (nextn <= 0) break;
        #pragma unroll
        for (int i = 0; i < 4; ++i) if (i < nextn) {
            cur[i][0] = nxt[i][0]; cur[i][1] = nxt[i][1];
        }
        curn = nextn; y = yn;
    }
}

// ---------------------------------------------------------------------------
// One kernel, three roles (round 9 = round-7 worker/bulk REVERT + fused out):
//   blockIdx 0..111   : row workers -- exact round-7 structure (223 us
//     verified; round-8 wave-decoupling regressed 20% via 8x flag traffic).
//     Changes: h_t stores are agent-scope (cross-XCD visible within this
//     kernel) and cell 195 publishes its per-slice flag (consumers need it).
//   blockIdx 112..307 : per-cell bulk WGs -- exact round-7 structure.
//   blockIdx 308..503 : fused gemm_y+softmax, one WG per pixel p. Spins on
//     uflag(p) (h_t(p) visible after the worker's drain barrier), computes
//     Y[b][ch] = 4*b_out + sum_k WoT[k][ch]*hsum[k][b], channel softmax,
//     writes out directly. Removes 2 kernel launches + the full-GPU gemm_y
//     tail: early pixels' output work hides under the wavefront.
//     Deadlock-free: 504 WGs <= 512 co-resident; consumers only read flags.
// ---------------------------------------------------------------------------
__global__ __launch_bounds__(512, 2) void rnn_dataflow(
    const float* __restrict__ A, const float* __restrict__ WhT,
    float* __restrict__ E, float* __restrict__ h_bulk,
    float* __restrict__ h_t, float* __restrict__ TLN,
    float* __restrict__ TLW, float* __restrict__ dsAcc,
    unsigned char* __restrict__ uflag, unsigned char* __restrict__ hflag,
    const float* __restrict__ WoT, const float* __restrict__ b_out,
    float* __restrict__ out) {
    __shared__ __align__(16) float hT8[CC * 8];   // full h [k][s], stride 8
    __shared__ __align__(16) float up[8 * 576];   // matvec partials [wave][c*9+s]
    __shared__ unsigned mbox;                     // bulk WG: ready-chunks bitmap
    __shared__ unsigned pf;                       // worker: uniform prefetch verdict
    int bid = blockIdx.x;
    int t = threadIdx.x;
    int lane = t & 63, wv = t >> 6;

    if (bid < NWORK) {
        // ================= row worker (round-7 structure) =================
        int px = bid >> 3, w = bid & 7;
        int ch = w * 64 + lane;                   // this thread's publish channel
        int m = wv >> 1, b = wv & 1;              // seq decode (s = wv)
        float wreg2[64];                          // WhT[64wv+kk][ch]
        #pragma unroll
        for (int kk = 0; kk < 64; ++kk)
            wreg2[kk] = WhT[(size_t)(wv * 64 + kk) * CC + ch];
        __builtin_amdgcn_s_setprio(1);

        float hb[8];
        float tnr[8], dsNr[8];    // loop-carried N-tail prefetch
        bool hb_ok = false;       // hb[] prefetched for upcoming cell? (uniform)
        bool n_ok  = false;       // tnr/dsNr prefetched? (uniform)

        for (int py = 0; py < WW; ++py) {
            int cell = px * WW + py;
            int cellN = cell - WW, cellW = cell - 1;

            // prefetch consumer-cell a values (overlaps the polls)
            float aSr = 0.f, aWr = 0.f;
            if (px < HH - 1) {
                int fi = (m & 2) ? (HH - 2 - px) : (px + 1);
                int fj = (m & 1) ? (WW - 1 - py) : py;
                aSr = A[((size_t)b * PP + fi * WW + fj) * CC + ch];
            }
            if (py < WW - 1) {
                int fi = (m & 2) ? (HH - 1 - px) : px;
                int fj = (m & 1) ? (WW - 2 - py) : (py + 1);
                aWr = A[((size_t)b * PP + fi * WW + fj) * CC + ch];
            }

            // phase 1 (fallback only, hb_ok uniform): observe + load h_bulk
            if (!hb_ok) {
                if (wv == 0 && lane == 0)
                    while (flag8_ld(hflag + (size_t)cell * 64) != ALL8)
                        __builtin_amdgcn_s_sleep(1);
                __syncthreads();
                asm volatile("" ::: "memory");
                #pragma unroll
                for (int s = 0; s < 8; ++s)
                    hb[s] = h_bulk[((size_t)cell * NSEQ + s) * CC + t];
            }

            // phase 2: W (and N only if not prefetched) ready?
            if (wv == 0) {
                while (true) {
                    unsigned ok = 1u;
                    if (lane == 0)      { if (py > 0) ok = (flag8_ld(uflag + (size_t)cellW * 64) == ALL8); }
                    else if (lane == 1) { if (px > 0 && !n_ok) ok = (flag8_ld(uflag + (size_t)cellN * 64) == ALL8); }
                    if (__ballot(ok != 0u) == ~0ull) break;
                    __builtin_amdgcn_s_sleep(1);
                }
            }
            __syncthreads();
            asm volatile("" ::: "memory");

            // load leg: N part only on prefetch miss; W always
            if (px > 0) {
                if (!n_ok) {
                    #pragma unroll
                    for (int i = 0; i < 8; ++i)
                        dsNr[i] = ldf_agent(&dsAcc[(size_t)cell * 16 + i]);
                    #pragma unroll
                    for (int s = 0; s < 8; ++s)
                        tnr[s] = ldf_agent(&TLN[((size_t)cell * NSEQ + s) * CC + t]);
                }
                #pragma unroll
                for (int s = 0; s < 8; ++s)
                    hb[s] += tnr[s] * __builtin_amdgcn_rcpf(dsNr[s]);
            }
            if (py > 0) {
                float dsw[8], tw[8];
                #pragma unroll
                for (int i = 0; i < 8; ++i)
                    dsw[i] = ldf_agent(&dsAcc[(size_t)cell * 16 + 8 + i]);
                #pragma unroll
                for (int s = 0; s < 8; ++s)
                    tw[s] = ldf_agent(&TLW[((size_t)cell * NSEQ + s) * CC + t]);
                #pragma unroll
                for (int s = 0; s < 8; ++s)
                    hb[s] += tw[s] * __builtin_amdgcn_rcpf(dsw[s]);
            }
            if (wv == w) {   // h_t: own 64-ch stripe, AGENT scope (fused consumer)
                #pragma unroll
                for (int s = 0; s < 8; ++s)
                    store_wt(&h_t[((size_t)cell * NSEQ + s) * CC + t], hb[s]);
            }
            *(float4*)&hT8[t * 8]     = make_float4(hb[0], hb[1], hb[2], hb[3]);
            *(float4*)&hT8[t * 8 + 4] = make_float4(hb[4], hb[5], hb[6], hb[7]);
            // no barrier: wave wv's matvec reads exactly its own threads' stripe
            if (cell == PP - 1) {
                // (13,13): no U consumer, but the fused out-WG needs h_t + flag
                __builtin_amdgcn_s_waitcnt(0);
                asm volatile("" ::: "memory");
                if (wv == w && lane == 0)
                    flag_st(uflag + (size_t)cell * 64 + w);
                break;
            }

            // matvec: wave wv owns k in [64wv, 64wv+64); lane owns channel.
            float acc[8] = {0.f,0.f,0.f,0.f,0.f,0.f,0.f,0.f};
            const float* hp = hT8 + (wv << 9);
            #pragma unroll
            for (int kk = 0; kk < 64; ++kk) {
                float4 h0 = *(const float4*)(hp + kk * 8);
                float4 h1 = *(const float4*)(hp + kk * 8 + 4);
                float wvv = wreg2[kk];
                acc[0] += wvv * h0.x; acc[1] += wvv * h0.y;
                acc[2] += wvv * h0.z; acc[3] += wvv * h0.w;
                acc[4] += wvv * h1.x; acc[5] += wvv * h1.y;
                acc[6] += wvv * h1.z; acc[7] += wvv * h1.w;
            }
            #pragma unroll
            for (int s = 0; s < 8; ++s)
                up[wv * 576 + lane * 9 + s] = acc[s];   // full overwrite, no zeroing
            __syncthreads();

            // publish: U, E = exp(U), consumer tails + denominator partials
            {
                float U = up[lane * 9 + wv];
                #pragma unroll
                for (int w2 = 1; w2 < 8; ++w2) U += up[w2 * 576 + lane * 9 + wv];
                float Ev = __expf(U);
                store_wt(&E[((size_t)wv * PP + cell) * CC + ch], Ev);
                float pdS = 0.f, pdW = 0.f;
                if (px < HH - 1) {
                    float pv = __expf(aSr) * Ev;
                    store_wt(&TLN[((size_t)(cell + WW) * NSEQ + wv) * CC + ch],
                             fmaxf(aSr + U, 0.f) * pv);
                    pdS = fmaxf(pv, 1.f);
                }
                if (py < WW - 1) {
                    float pv = __expf(aWr) * Ev;
                    store_wt(&TLW[((size_t)(cell + 1) * NSEQ + wv) * CC + ch],
                             fmaxf(aWr + U, 0.f) * pv);
                    pdW = fmaxf(pv, 1.f);
                }
                #pragma unroll
                for (int off = 32; off; off >>= 1) {
                    pdS += __shfl_xor(pdS, off, 64);
                    pdW += __shfl_xor(pdW, off, 64);
                }
                if (lane == 0) {
                    if (px < HH - 1)
                        unsafeAtomicAdd(&dsAcc[(size_t)(cell + WW) * 16 + wv], pdS);
                    if (py < WW - 1)
                        unsafeAtomicAdd(&dsAcc[(size_t)(cell + 1) * 16 + 8 + wv], pdW);
                }
            }

            // uniform prefetch verdicts for cell+1 (ONE reader, LDS broadcast):
            //   bit0: h_bulk(cell+1) ready   bit1: N(cell+1) publishes ready
            if (t == 0) {
                unsigned v = 0u;
                if (py + 1 < WW) {
                    if (flag8_ld(hflag + (size_t)(cell + 1) * 64) == ALL8) v |= 1u;
                    if (px > 0 &&
                        flag8_ld(uflag + (size_t)(cellN + 1) * 64) == ALL8) v |= 2u;
                }
                pf = v;
            }

            __syncthreads();     // drain: stores/atomics acked; pf visible
            if (t == 0) flag_st(uflag + (size_t)cell * 64 + w);   // byte, no RMW

            hb_ok = false; n_ok = false;
            if (py + 1 < WW) {
                unsigned v = pf;
                if (v & 1u) {
                    #pragma unroll
                    for (int s = 0; s < 8; ++s)
                        hb[s] = h_bulk[((size_t)(cell + 1) * NSEQ + s) * CC + t];
                    hb_ok = true;
                }
                if (v & 2u) {    // px > 0 guaranteed by verdict
                    #pragma unroll
                    for (int i = 0; i < 8; ++i)
                        dsNr[i] = ldf_agent(&dsAcc[(size_t)(cell + 1) * 16 + i]);
                    #pragma unroll
                    for (int s = 0; s < 8; ++s)
                        tnr[s] = ldf_agent(&TLN[((size_t)(cell + 1) * NSEQ + s) * CC + t]);
                    n_ok = true;
                }
            }
        }
    } else if (bid < NWORK + PP) {
        // ================= bulk window WG (chunked rows), off-path ==========
        int cell = bid - NWORK;
        int px = cell / WW, py = cell % WW;
        int s = wv, m = s >> 1, b = s & 1;
        int fi = (m & 2) ? (HH-1-px) : px;
        int fj = (m & 1) ? (WW-1-py) : py;
        int cb = lane * 4;

        if (t == 0) mbox = 0u;
        __syncthreads();          // once, at WG start (long before deps ready)

        const float* acur = A + ((size_t)b * PP + fi * WW + fj) * CC;
        float4 a0 = *(const float4*)(acur + cb);
        float4 a1 = *(const float4*)(acur + cb + 256);
        float ar[8] = {a0.x,a0.y,a0.z,a0.w,a1.x,a1.y,a1.z,a1.w};
        float er[8];
        #pragma unroll
        for (int j = 0; j < 8; ++j) er[j] = __expf(ar[j]);
        float hacc[8] = {0.f,0.f,0.f,0.f,0.f,0.f,0.f,0.f};

        {   // self pixel first (needs no U at all): U=0 -> E=1
            float ds = 0.f, tl[8];
            #pragma unroll
            for (int j = 0; j < 8; ++j) {
                float pv = er[j];
                ds += fmaxf(pv, 1.0f);
                tl[j] = fmaxf(ar[j], 0.0f) * pv;
            }
            #pragma unroll
            for (int off = 32; off; off >>= 1) ds += __shfl_xor(ds, off, 64);
            float rd = 1.0f / ds;
            #pragma unroll
            for (int j = 0; j < 8; ++j) hacc[j] += tl[j] * rd;
        }

        const float* Eb = E + (size_t)s * PP * CC;
        // chunk slots: slot = lane, row x = lane>>1, phase = lane&1.
        int sx = lane >> 1, sph = lane & 1;
        int gate = -1;
        if (sx <= px) {
            int L = (sx <= px-2) ? py : ((sx == px-1) ? py-1 : py-2);
            if (L >= 0) {
                if (L <= 2) { if (sph == 0) gate = sx * WW + L; }
                else gate = sx * WW + (sph ? L : (L - 3));
            }
        }
        unsigned pend = (unsigned)__ballot(gate >= 0);

        if (wv == 0) {
            unsigned done = 0u;
            while (pend) {
                bool rdy = true;
                if (gate >= 0 && ((pend >> lane) & 1u))
                    rdy = (flag8_ld(uflag + (size_t)gate * 64) == ALL8);
                unsigned newly = pend & (unsigned)__ballot(rdy);
                if (!newly) { __builtin_amdgcn_s_sleep(2); continue; }
                done |= newly;
                __hip_atomic_store(&mbox, done, __ATOMIC_RELAXED,
                                   __HIP_MEMORY_SCOPE_WORKGROUP);
                asm volatile("" ::: "memory");
                unsigned go = newly;
                while (go) {
                    int sl = __ffs(go) - 1; go &= go - 1;
                    int xx = sl >> 1;
                    int L = (xx <= px-2) ? py : ((xx == px-1) ? py-1 : py-2);
                    int yy0 = 0, yy1 = L;
                    if (L > 2) { if (sl & 1) yy0 = L - 2; else yy1 = L - 3; }
                    proc_row(Eb + (size_t)(xx * WW + yy0) * CC + cb,
                             yy1 - yy0 + 1, ar, er, hacc);
                }
                pend &= ~newly;
            }
        } else {
            while (pend) {
                unsigned d = __hip_atomic_load(&mbox, __ATOMIC_RELAXED,
                                               __HIP_MEMORY_SCOPE_WORKGROUP);
                unsigned newly = d & pend;
                if (!newly) { __builtin_amdgcn_s_sleep(2); continue; }
                asm volatile("" ::: "memory");
                unsigned go = newly;
                while (go) {
                    int sl = __ffs(go) - 1; go &= go - 1;
                    int xx = sl >> 1;
                    int L = (xx <= px-2) ? py : ((xx == px-1) ? py-1 : py-2);
                    int yy0 = 0, yy1 = L;
                    if (L > 2) { if (sl & 1) yy0 = L - 2; else yy1 = L - 3; }
                    proc_row(Eb + (size_t)(xx * WW + yy0) * CC + cb,
                             yy1 - yy0 + 1, ar, er, hacc);
                }
                pend &= ~newly;
            }
        }

        // per-wave publish h_bulk: contiguous WT stores + drain + byte flag
        float* hp = h_bulk + ((size_t)cell * NSEQ + s) * CC;
        #pragma unroll
        for (int j = 0; j < 4; ++j) {
            store_wt(hp + cb + j,       hacc[j]);
            store_wt(hp + cb + 256 + j, hacc[4 + j]);
        }
        __builtin_amdgcn_s_waitcnt(0);
        asm volatile("" ::: "memory");
        if (lane == 0) flag_st(hflag + (size_t)cell * 64 + s);
    } else {
        // ================= fused gemm_y + softmax, one WG per pixel =========
        int p = bid - NWORK - PP;
        float2* hs2 = (float2*)hT8;               // [k] -> (hsum_b0, hsum_b1)
        float (*redm)[2] = (float (*)[2])up;      // per-wave max partials
        float (*reds)[2] = (float (*)[2])(up + 64); // per-wave sum partials

        if (t == 0)
            while (flag8_ld(uflag + (size_t)p * 64) != ALL8)
                __builtin_amdgcn_s_sleep(8);
        __syncthreads();
        asm volatile("" ::: "memory");

        {   // stage hsum[k][b] = sum_m h_t[p][2m+b][k]
            float v[8];
            #pragma unroll
            for (int s = 0; s < 8; ++s)
                v[s] = ldf_agent(&h_t[((size_t)p * NSEQ + s) * CC + t]);
            hs2[t] = make_float2(v[0]+v[2]+v[4]+v[6], v[1]+v[3]+v[5]+v[7]);
        }
        __syncthreads();

        float y0 = 4.0f * b_out[t], y1 = y0;      // ch = t
        for (int k0 = 0; k0 < CC; k0 += 8) {
            float wk[8];
            #pragma unroll
            for (int j = 0; j < 8; ++j)
                wk[j] = WoT[(size_t)(k0 + j) * CC + t];
            #pragma unroll
            for (int j = 0; j < 8; ++j) {
                float2 hk = hs2[k0 + j];          // LDS broadcast, conflict-free
                y0 += wk[j] * hk.x;
                y1 += wk[j] * hk.y;
            }
        }

        // softmax over channels (512 threads = 512 ch), per batch b
        float m0 = y0, m1 = y1;
        #pragma unroll
        for (int off = 32; off; off >>= 1) {
            m0 = fmaxf(m0, __shfl_xor(m0, off, 64));
            m1 = fmaxf(m1, __shfl_xor(m1, off, 64));
        }
        if (lane == 0) { redm[wv][0] = m0; redm[wv][1] = m1; }
        __syncthreads();
        float gm0 = redm[0][0], gm1 = redm[0][1];
        #pragma unroll
        for (int i = 1; i < 8; ++i) {
            gm0 = fmaxf(gm0, redm[i][0]);
            gm1 = fmaxf(gm1, redm[i][1]);
        }
        float e0 = expf(y0 - gm0), e1 = expf(y1 - gm1);
        float s0 = e0, s1 = e1;
        #pragma unroll
        for (int off = 32; off; off >>= 1) {
            s0 += __shfl_xor(s0, off, 64);
            s1 += __shfl_xor(s1, off, 64);
        }
        if (lane == 0) { reds[wv][0] = s0; reds[wv][1] = s1; }
        __syncthreads();
        float t0 = 0.f, t1 = 0.f;
        #pragma unroll
        for (int i = 0; i < 8; ++i) { t0 += reds[i][0]; t1 += reds[i][1]; }
        out[((size_t)0 * CC + t) * PP + p] = e0 * (1.0f / t0);
        out[((size_t)1 * CC + t) * PP + p] = e1 * (1.0f / t1);
    }
}

// ---------------------------------------------------------------------------
extern "C" void kernel_launch(void* const* d_in, const int* in_sizes, int n_in,
                              void* d_out, int out_size, void* d_ws, size_t ws_size,
                              hipStream_t stream) {
    const float* X     = (const float*)d_in[0];
    const float* Wx    = (const float*)d_in[1];
    const float* Wh    = (const float*)d_in[2];
    const float* b_in  = (const float*)d_in[3];
    const float* Wo    = (const float*)d_in[4];
    const float* b_out = (const float*)d_in[5];
    float* out = (float*)d_out;

    float* ws     = (float*)d_ws;
    float* WhT    = ws;                     // 262144
    float* A      = WhT    + 262144;        // 200704
    float* E      = A      + 200704;        // 802816  [s][cell][c] = exp(U)
    float* h_bulk = E      + 802816;        // 802816  [cell][s][c]
    float* h_t    = h_bulk + 802816;        // 802816  [cell][s][c] full h
    float* TLN    = h_t    + 802816;        // 802816  [cell][s][c] tail from North
    float* TLW    = TLN    + 802816;        // 802816  [cell][s][c] tail from West
    float* WoT    = TLW    + 802816;        // 262144  Wo transposed
    unsigned char* uflag = (unsigned char*)(WoT + 262144);  // PP*64 B
    unsigned char* hflag = uflag + PP * 64;                 // PP*64 B
    float* dsAcc = (float*)(hflag + PP * 64);               // PP*16: [cell][N|W]

    hipLaunchKernelGGL(prep, dim3(737), dim3(256), 0, stream,
                       Wx, X, b_in, Wh, Wo, A, WhT, WoT, (unsigned*)uflag);
    hipLaunchKernelGGL(rnn_dataflow, dim3(NWORK + PP + PP), dim3(512), 0, stream,
                       A, WhT, E, h_bulk, h_t, TLN, TLW, dsAcc, uflag, hflag,
                       WoT, b_out, out);
}